// Round 3
// baseline (583.371 us; speedup 1.0000x reference)
//
#include <hip/hip_runtime.h>
#include <hip/hip_bf16.h>

// Disable FMA contraction globally: the numpy f32 reference has no FMA, and
// the contact decision (dh <= 0) is discontinuous -> must match op-for-op.
#pragma clang fp contract(off)

static constexpr int Bc    = 512;
static constexpr int NPTSc = 2048;
static constexpr int Hc    = 256;
static constexpr int Wc    = 256;
static constexpr float DMAXF = 6.4f;

__device__ __forceinline__ float bilerp(const float* __restrict__ g, int base,
                                        int i0, int j0, float wi, float wj) {
#pragma clang fp contract(off)
    float g00 = g[base + i0 * Wc + j0];
    float g01 = g[base + i0 * Wc + j0 + 1];
    float g10 = g[base + (i0 + 1) * Wc + j0];
    float g11 = g[base + (i0 + 1) * Wc + j0 + 1];
    // exact op ordering of the reference
    return g00 * (1.0f - wi) * (1.0f - wj)
         + g01 * (1.0f - wi) * wj
         + g10 * wi * (1.0f - wj)
         + g11 * wi * wj;
}

__global__ __launch_bounds__(256)
void phys_points(const float* __restrict__ x, const float* __restrict__ xd,
                 const float* __restrict__ R, const float* __restrict__ omega,
                 const float* __restrict__ rp,
                 const float* __restrict__ zg, const float* __restrict__ zgg,
                 const float* __restrict__ kg, const float* __restrict__ dg,
                 const float* __restrict__ mug,
                 const int* __restrict__ dparts, const float* __restrict__ ctrl,
                 float* __restrict__ outFs, float* __restrict__ outFf,
                 float* __restrict__ acc)
{
#pragma clang fp contract(off)
    const int tid = threadIdx.x;
    const int b = blockIdx.x >> 3;               // NPTS/256 = 8 blocks per batch
    const int n = ((blockIdx.x & 7) << 8) + tid;

    // per-batch scalars (broadcast loads, L1-served)
    float xb0 = x[b * 3 + 0], xb1 = x[b * 3 + 1], xb2 = x[b * 3 + 2];
    float xd0 = xd[b * 3 + 0], xd1 = xd[b * 3 + 1], xd2 = xd[b * 3 + 2];
    float om0 = omega[b * 3 + 0], om1 = omega[b * 3 + 1], om2 = omega[b * 3 + 2];
    float R00 = R[b * 9 + 0], R01 = R[b * 9 + 1], R02 = R[b * 9 + 2];
    float R10 = R[b * 9 + 3], R11 = R[b * 9 + 4], R12 = R[b * 9 + 5];
    float R20 = R[b * 9 + 6], R21 = R[b * 9 + 7], R22 = R[b * 9 + 8];

    const int part = dparts[n];
    const float cpart = ctrl[b * 4 + part];

    const int pbase = (b * NPTSc + n) * 3;
    float p0 = rp[pbase + 0], p1 = rp[pbase + 1], p2 = rp[pbase + 2];

    // x_points = R @ p + x  (left-to-right sum, then add x)
    float xp0 = (R00 * p0 + R01 * p1 + R02 * p2) + xb0;
    float xp1 = (R10 * p0 + R11 * p1 + R12 * p2) + xb1;
    float xp2 = (R20 * p0 + R21 * p1 + R22 * p2) + xb2;

    // r = x_points - x  (reference recomputes this incl. the +x/-x round-trip)
    float rx = xp0 - xb0, ry = xp1 - xb1, rz = xp2 - xb2;

    // bilinear indices
    float gi = (xp0 + DMAXF) / (2.0f * DMAXF) * 255.0f;
    gi = fminf(fmaxf(gi, 0.0f), 255.0f);
    float gj = (xp1 + DMAXF) / (2.0f * DMAXF) * 255.0f;
    gj = fminf(fmaxf(gj, 0.0f), 255.0f);
    int i0 = (int)floorf(gi); i0 = min(max(i0, 0), Hc - 2);
    int j0 = (int)floorf(gj); j0 = min(max(j0, 0), Wc - 2);
    float wi = gi - (float)i0;
    float wj = gj - (float)j0;

    const int gb = b * (Hc * Wc);
    float zp  = bilerp(zg,  gb, i0, j0, wi, wj);
    float kp  = bilerp(kg,  gb, i0, j0, wi, wj);
    float dpv = bilerp(dg,  gb, i0, j0, wi, wj);
    float mup = bilerp(mug, gb, i0, j0, wi, wj);
    const int gb2 = b * (2 * Hc * Wc);
    float gx = bilerp(zgg, gb2, i0, j0, wi, wj);
    float gy = bilerp(zgg, gb2 + Hc * Wc, i0, j0, wi, wj);

    float dh = xp2 - zp;
    bool on_grid = (xp0 >= -DMAXF) && (xp0 <= DMAXF) &&
                   (xp1 >= -DMAXF) && (xp1 <= DMAXF);
    float contact = ((dh <= 0.0f) && on_grid) ? 1.0f : 0.0f;

    // surface normal
    float nx = -gx, ny = -gy, nz = 1.0f;
    float nn = sqrtf(nx * nx + ny * ny + nz * nz);
    nx /= nn; ny /= nn; nz /= nn;

    // point velocity: xd + omega x r
    float vx = xd0 + (om1 * rz - om2 * ry);
    float vy = xd1 + (om2 * rx - om0 * rz);
    float vz = xd2 + (om0 * ry - om1 * rx);

    float xdn = vx * nx + vy * ny + vz * nz;
    float s = -(kp * dh + dpv * xdn);
    const float scale = contact * (1.0f / 2048.0f);  // contact in {0,1}; /2048 exact
    float Fs0 = (s * nx) * scale;
    float Fs1 = (s * ny) * scale;
    float Fs2 = (s * nz) * scale;

    float Nmag = sqrtf(Fs0 * Fs0 + Fs1 * Fs1 + Fs2 * Fs2);

    // thrust dir = normalize(R[:,0])
    float t0 = R00, t1 = R10, t2 = R20;
    float tn = sqrtf(t0 * t0 + t1 * t1 + t2 * t2);
    t0 /= tn; t1 /= tn; t2 /= tn;

    float dv0 = cpart * t0 - vx;
    float dv1 = cpart * t1 - vy;
    float dv2 = cpart * t2 - vz;
    float dvn = dv0 * nx + dv1 * ny + dv2 * nz;
    float dt0 = dv0 - dvn * nx;
    float dt1 = dv1 - dvn * ny;
    float dt2 = dv2 - dvn * nz;
    float mN = mup * Nmag;
    float Ff0 = mN * tanhf(dt0);
    float Ff1 = mN * tanhf(dt1);
    float Ff2 = mN * tanhf(dt2);

    // write per-point outputs (f32)
    outFs[pbase + 0] = Fs0;
    outFs[pbase + 1] = Fs1;
    outFs[pbase + 2] = Fs2;
    outFf[pbase + 0] = Ff0;
    outFf[pbase + 1] = Ff1;
    outFf[pbase + 2] = Ff2;

    // torque = cross(r, Fs + Ff)
    float Ft0 = Fs0 + Ff0, Ft1 = Fs1 + Ff1, Ft2 = Fs2 + Ff2;
    float vals[9];
    vals[0] = ry * Ft2 - rz * Ft1;
    vals[1] = rz * Ft0 - rx * Ft2;
    vals[2] = rx * Ft1 - ry * Ft0;
    vals[3] = Fs0; vals[4] = Fs1; vals[5] = Fs2;
    vals[6] = Ff0; vals[7] = Ff1; vals[8] = Ff2;

    // wave-64 butterfly reduction, then one atomic per wave-leader per value
    #pragma unroll
    for (int k = 0; k < 9; ++k) {
        float v = vals[k];
        #pragma unroll
        for (int off = 32; off > 0; off >>= 1)
            v += __shfl_xor(v, off, 64);
        vals[k] = v;
    }
    if ((tid & 63) == 0) {
        float* ab = acc + b * 12;
        #pragma unroll
        for (int k = 0; k < 9; ++k) atomicAdd(ab + k, vals[k]);
    }
}

__global__ __launch_bounds__(256)
void phys_final(const float* __restrict__ xd, const float* __restrict__ Imat,
                const float* __restrict__ acc,
                float* __restrict__ out_xd, float* __restrict__ out_xdd,
                float* __restrict__ out_omd)
{
#pragma clang fp contract(off)
    int b = blockIdx.x * blockDim.x + threadIdx.x;
    if (b >= Bc) return;
    const float* ab = acc + b * 12;
    float tq0 = ab[0], tq1 = ab[1], tq2 = ab[2];
    float sFs0 = ab[3], sFs1 = ab[4], sFs2 = ab[5];
    float sFf0 = ab[6], sFf1 = ab[7], sFf2 = ab[8];

    float a00 = Imat[b * 9 + 0], a01 = Imat[b * 9 + 1], a02 = Imat[b * 9 + 2];
    float a10 = Imat[b * 9 + 3], a11 = Imat[b * 9 + 4], a12 = Imat[b * 9 + 5];
    float a20 = Imat[b * 9 + 6], a21 = Imat[b * 9 + 7], a22 = Imat[b * 9 + 8];

    // adjugate / determinant inverse (I is well-conditioned: A A^T + 2I)
    float c00 = a11 * a22 - a12 * a21;
    float c01 = a02 * a21 - a01 * a22;
    float c02 = a01 * a12 - a02 * a11;
    float c10 = a12 * a20 - a10 * a22;
    float c11 = a00 * a22 - a02 * a20;
    float c12 = a02 * a10 - a00 * a12;
    float c20 = a10 * a21 - a11 * a20;
    float c21 = a01 * a20 - a00 * a21;
    float c22 = a00 * a11 - a01 * a10;
    float det = a00 * c00 + a01 * c10 + a02 * c20;
    float id = 1.0f / det;

    float od0 = (c00 * tq0 + c01 * tq1 + c02 * tq2) * id;
    float od1 = (c10 * tq0 + c11 * tq1 + c12 * tq2) * id;
    float od2 = (c20 * tq0 + c21 * tq1 + c22 * tq2) * id;

    // F_cog = (grav + sum Fs) + sum Ff ; xdd = F_cog / MASS
    float fc0 = (0.0f + sFs0) + sFf0;
    float fc1 = (0.0f + sFs1) + sFf1;
    float fc2 = (-40.0f * 9.8f + sFs2) + sFf2;
    float xdd0 = fc0 / 40.0f, xdd1 = fc1 / 40.0f, xdd2 = fc2 / 40.0f;

    out_xd[b * 3 + 0] = xd[b * 3 + 0];
    out_xd[b * 3 + 1] = xd[b * 3 + 1];
    out_xd[b * 3 + 2] = xd[b * 3 + 2];
    out_xdd[b * 3 + 0] = xdd0;
    out_xdd[b * 3 + 1] = xdd1;
    out_xdd[b * 3 + 2] = xdd2;
    out_omd[b * 3 + 0] = od0;
    out_omd[b * 3 + 1] = od1;
    out_omd[b * 3 + 2] = od2;
}

extern "C" void kernel_launch(void* const* d_in, const int* in_sizes, int n_in,
                              void* d_out, int out_size, void* d_ws, size_t ws_size,
                              hipStream_t stream)
{
    const float* x    = (const float*)d_in[0];
    const float* xd   = (const float*)d_in[1];
    const float* R    = (const float*)d_in[2];
    const float* om   = (const float*)d_in[3];
    const float* Imat = (const float*)d_in[4];
    const float* rp   = (const float*)d_in[5];
    const float* zg   = (const float*)d_in[6];
    const float* zgg  = (const float*)d_in[7];
    const float* kg   = (const float*)d_in[8];
    const float* dg   = (const float*)d_in[9];
    const float* mug  = (const float*)d_in[10];
    const int* dparts = (const int*)d_in[11];
    const float* ctrl = (const float*)d_in[12];

    float* out = (float*)d_out;
    const int B3 = Bc * 3;
    float* out_xd  = out;
    float* out_xdd = out + B3;
    float* out_omd = out + 2 * B3;
    float* outFs   = out + 3 * B3;
    float* outFf   = out + 3 * B3 + (size_t)Bc * NPTSc * 3;

    float* acc = (float*)d_ws;
    hipMemsetAsync(d_ws, 0, Bc * 12 * sizeof(float), stream);

    phys_points<<<Bc * NPTSc / 256, 256, 0, stream>>>(
        x, xd, R, om, rp, zg, zgg, kg, dg, mug, dparts, ctrl, outFs, outFf, acc);
    phys_final<<<(Bc + 255) / 256, 256, 0, stream>>>(
        xd, Imat, acc, out_xd, out_xdd, out_omd);
}